// Round 1
// baseline (30877.649 us; speedup 1.0000x reference)
//
#include <hip/hip_runtime.h>

#define T_STEPS 1024
#define FDIM    2048
#define LAT     128
#define HID     256
#define G3      384     // 3*LAT
#define MB      8       // features per block
#define NTHR    256

__device__ __forceinline__ float sigmoidf_(float x) {
    // safe: exp(-x) -> inf for very negative x gives 1/inf = 0
    return 1.0f / (1.0f + __expf(-x));
}
__device__ __forceinline__ float tanhf_(float x) {
    // tanh(x) = sign(x) * (1 - e^{-2|x|}) / (1 + e^{-2|x|}); e in (0,1], no inf/inf
    float ax = fabsf(x);
    float e  = __expf(-2.0f * ax);
    float t  = (1.0f - e) / (1.0f + e);
    return copysignf(t, x);
}

// Transpose weights into workspace for coalesced per-step streaming.
// W1  (HID, LAT)  -> W1T  [LAT][HID]
// W2  (LAT, HID)  -> W2T  [HID][LAT]
// Whh (G3,  LAT)  -> WhhT [LAT][G3]
__global__ void prep_weights(const float* __restrict__ W1,
                             const float* __restrict__ W2,
                             const float* __restrict__ Whh,
                             float* __restrict__ W1T,
                             float* __restrict__ W2T,
                             float* __restrict__ WhhT)
{
    int tid = blockIdx.x * blockDim.x + threadIdx.x;
    if (tid < HID * LAT) {
        int r = tid / LAT, c = tid % LAT;      // W1[r][c]
        W1T[c * HID + r] = W1[tid];
    }
    if (tid < LAT * HID) {
        int r = tid / HID, c = tid % HID;      // W2[r][c]
        W2T[c * LAT + r] = W2[tid];
    }
    if (tid < G3 * LAT) {
        int r = tid / LAT, c = tid % LAT;      // Whh[r][c]
        WhhT[c * G3 + r] = Whh[tid];
    }
}

__global__ __launch_bounds__(NTHR)
void odernn_kernel(const float* __restrict__ times,
                   const float* __restrict__ vals,
                   const float* __restrict__ mask,
                   const float* __restrict__ W1T, const float* __restrict__ b1,
                   const float* __restrict__ W2T, const float* __restrict__ b2,
                   const float* __restrict__ W_ih, const float* __restrict__ b_ih,
                   const float* __restrict__ WhhT, const float* __restrict__ b_hh,
                   float* __restrict__ out)
{
    __shared__ float h_s[MB][LAT];     // 4 KB   per-feature hidden state
    __shared__ float u_s[MB][HID];     // 8 KB   tanh(W1 h + b1)
    __shared__ float g_s[MB][512];     // 16 KB  phase-2 partials, then gh preacts

    const int j = threadIdx.x;
    const int fbase = blockIdx.x * MB;

    for (int e = j; e < MB * LAT; e += NTHR) (&h_s[0][0])[e] = 0.0f;
    __syncthreads();

    for (int t = 0; t < T_STEPS; ++t) {
        // dts[t] = (t==0) ? 0 : rev_t[t-1]-rev_t[t] = times[T-t] - times[T-1-t]
        const float dt = (t == 0) ? 0.0f
                         : (times[T_STEPS - t] - times[T_STEPS - 1 - t]);

        if (dt > 0.0f) {
            // ---------- phase 1: u = tanh(h @ W1^T + b1), output j per thread
            float acc[MB];
            {
                const float bj = b1[j];
                #pragma unroll
                for (int m = 0; m < MB; ++m) acc[m] = bj;
            }
            for (int k = 0; k < LAT; k += 4) {
                const float w0 = W1T[(k + 0) * HID + j];
                const float w1 = W1T[(k + 1) * HID + j];
                const float w2 = W1T[(k + 2) * HID + j];
                const float w3 = W1T[(k + 3) * HID + j];
                #pragma unroll
                for (int m = 0; m < MB; ++m) {
                    const float4 h4 = *(const float4*)(&h_s[m][k]);
                    acc[m] = fmaf(w0, h4.x, acc[m]);
                    acc[m] = fmaf(w1, h4.y, acc[m]);
                    acc[m] = fmaf(w2, h4.z, acc[m]);
                    acc[m] = fmaf(w3, h4.w, acc[m]);
                }
            }
            #pragma unroll
            for (int m = 0; m < MB; ++m) u_s[m][j] = tanhf_(acc[m]);
            __syncthreads();

            // ---------- phase 2: ode = u @ W2^T + b2, split-K over two halves
            {
                const int p    = j & (LAT - 1);
                const int half = j >> 7;              // 0 or 1
                const int k0   = half * (HID / 2);
                float acc2[MB];
                const float binit = (half == 0) ? b2[p] : 0.0f;
                #pragma unroll
                for (int m = 0; m < MB; ++m) acc2[m] = binit;
                for (int k = k0; k < k0 + HID / 2; k += 4) {
                    const float w0 = W2T[(k + 0) * LAT + p];
                    const float w1 = W2T[(k + 1) * LAT + p];
                    const float w2 = W2T[(k + 2) * LAT + p];
                    const float w3 = W2T[(k + 3) * LAT + p];
                    #pragma unroll
                    for (int m = 0; m < MB; ++m) {
                        const float4 u4 = *(const float4*)(&u_s[m][k]);
                        acc2[m] = fmaf(w0, u4.x, acc2[m]);
                        acc2[m] = fmaf(w1, u4.y, acc2[m]);
                        acc2[m] = fmaf(w2, u4.z, acc2[m]);
                        acc2[m] = fmaf(w3, u4.w, acc2[m]);
                    }
                }
                #pragma unroll
                for (int m = 0; m < MB; ++m) g_s[m][half * LAT + p] = acc2[m];
            }
            __syncthreads();
            // finalize h += dt * ode
            if (j < LAT) {
                #pragma unroll
                for (int m = 0; m < MB; ++m)
                    h_s[m][j] = fmaf(dt, g_s[m][j] + g_s[m][LAT + j], h_s[m][j]);
            }
            __syncthreads();
        }

        // ---------- phase 3: gh = h @ Whh^T + b_hh  (384 outputs)
        // out j in [0,256) full-K per thread; out 256+p split-K across halves
        {
            float accA[MB], accB[MB];
            const float bA    = b_hh[j];
            const int   p     = j & (LAT - 1);
            const int   bhalf = j >> 7;
            const float bB    = (bhalf == 0) ? b_hh[2 * LAT + p] : 0.0f;
            #pragma unroll
            for (int m = 0; m < MB; ++m) { accA[m] = bA; accB[m] = bB; }
            const int bk0 = bhalf * (LAT / 2);
            for (int k = 0; k < LAT; k += 4) {
                const float wa0 = WhhT[(k + 0) * G3 + j];
                const float wa1 = WhhT[(k + 1) * G3 + j];
                const float wa2 = WhhT[(k + 2) * G3 + j];
                const float wa3 = WhhT[(k + 3) * G3 + j];
                const bool doB = (k >= bk0) && (k < bk0 + LAT / 2);
                float wb0 = 0.f, wb1 = 0.f, wb2 = 0.f, wb3 = 0.f;
                if (doB) {
                    wb0 = WhhT[(k + 0) * G3 + 2 * LAT + p];
                    wb1 = WhhT[(k + 1) * G3 + 2 * LAT + p];
                    wb2 = WhhT[(k + 2) * G3 + 2 * LAT + p];
                    wb3 = WhhT[(k + 3) * G3 + 2 * LAT + p];
                }
                #pragma unroll
                for (int m = 0; m < MB; ++m) {
                    const float4 h4 = *(const float4*)(&h_s[m][k]);
                    accA[m] = fmaf(wa0, h4.x, accA[m]);
                    accA[m] = fmaf(wa1, h4.y, accA[m]);
                    accA[m] = fmaf(wa2, h4.z, accA[m]);
                    accA[m] = fmaf(wa3, h4.w, accA[m]);
                    if (doB) {
                        accB[m] = fmaf(wb0, h4.x, accB[m]);
                        accB[m] = fmaf(wb1, h4.y, accB[m]);
                        accB[m] = fmaf(wb2, h4.z, accB[m]);
                        accB[m] = fmaf(wb3, h4.w, accB[m]);
                    }
                }
            }
            #pragma unroll
            for (int m = 0; m < MB; ++m) g_s[m][j] = accA[m];
            #pragma unroll
            for (int m = 0; m < MB; ++m) g_s[m][2 * LAT + bhalf * LAT + p] = accB[m];
        }
        __syncthreads();

        // ---------- phase 4: elementwise GRU update with mask
        {
            const size_t rowoff = (size_t)(T_STEPS - 1 - t) * FDIM + fbase;
            #pragma unroll
            for (int i = 0; i < (MB * LAT) / NTHR; ++i) {   // 4 iterations
                const int e = j + i * NTHR;
                const int m = e >> 7;
                const int k = e & (LAT - 1);
                const float x   = vals[rowoff + m];
                const float mk  = mask[rowoff + m];
                const float hv  = h_s[m][k];
                const float gir = fmaf(x, W_ih[k],           b_ih[k]);
                const float giz = fmaf(x, W_ih[LAT + k],     b_ih[LAT + k]);
                const float gin = fmaf(x, W_ih[2 * LAT + k], b_ih[2 * LAT + k]);
                const float r   = sigmoidf_(gir + g_s[m][k]);
                const float z   = sigmoidf_(giz + g_s[m][LAT + k]);
                const float ghn = g_s[m][2 * LAT + k] + g_s[m][3 * LAT + k];
                const float n   = tanhf_(fmaf(r, ghn, gin));
                const float hc  = (1.0f - z) * n + z * hv;
                h_s[m][k] = mk * hc + (1.0f - mk) * hv;
            }
        }
        __syncthreads();
    }

    for (int e = j; e < MB * LAT; e += NTHR) {
        const int m = e >> 7;
        const int k = e & (LAT - 1);
        out[(size_t)(fbase + m) * LAT + k] = h_s[m][k];
    }
}

extern "C" void kernel_launch(void* const* d_in, const int* in_sizes, int n_in,
                              void* d_out, int out_size, void* d_ws, size_t ws_size,
                              hipStream_t stream) {
    const float* times = (const float*)d_in[0];
    const float* vals  = (const float*)d_in[1];
    const float* mask  = (const float*)d_in[2];
    const float* W1    = (const float*)d_in[3];
    const float* b1    = (const float*)d_in[4];
    const float* W2    = (const float*)d_in[5];
    const float* b2    = (const float*)d_in[6];
    const float* W_ih  = (const float*)d_in[7];
    const float* b_ih  = (const float*)d_in[8];
    const float* Whh   = (const float*)d_in[9];
    const float* b_hh  = (const float*)d_in[10];
    float* out = (float*)d_out;

    float* W1T  = (float*)d_ws;            // LAT*HID   = 32768 floats
    float* W2T  = W1T + HID * LAT;         // HID*LAT   = 32768 floats
    float* WhhT = W2T + LAT * HID;         // LAT*G3    = 49152 floats
    // total ws need: 114688 floats = 448 KiB

    prep_weights<<<(G3 * LAT + 255) / 256, 256, 0, stream>>>(W1, W2, Whh, W1T, W2T, WhhT);
    odernn_kernel<<<FDIM / MB, NTHR, 0, stream>>>(times, vals, mask,
                                                  W1T, b1, W2T, b2,
                                                  W_ih, b_ih, WhhT, b_hh, out);
}

// Round 3
// 13918.867 us; speedup vs baseline: 2.2184x; 2.2184x over previous
//
#include <hip/hip_runtime.h>

#define T_STEPS 1024
#define FDIM    2048
#define LAT     128
#define HID     256
#define G3      384     // 3*LAT
#define MB      8       // features per block
#define NTHR    1024    // 16 waves; grid = 256 blocks = 1 block/CU

__device__ __forceinline__ float sigmoidf_(float x) {
    return 1.0f / (1.0f + __expf(-x));
}
__device__ __forceinline__ float tanhf_(float x) {
    float ax = fabsf(x);
    float e  = __expf(-2.0f * ax);
    float t  = (1.0f - e) / (1.0f + e);
    return copysignf(t, x);
}

// Pack weights so a thread's 4 consecutive k's for output o are one float4,
// while consecutive outputs stay adjacent for wave coalescing:
//   WP[(k>>2)*NOUT + o] (as float4) = { W[o][k..k+3] }
__global__ void prep_weights(const float* __restrict__ W1,   // (HID, LAT)
                             const float* __restrict__ W2,   // (LAT, HID)
                             const float* __restrict__ Whh,  // (G3,  LAT)
                             float* __restrict__ W1P,
                             float* __restrict__ W2P,
                             float* __restrict__ WhhP)
{
    int tid = blockIdx.x * blockDim.x + threadIdx.x;
    if (tid < HID * LAT) {              // W1: o in [0,256), k in [0,128)
        int o = tid / LAT, k = tid % LAT;
        W1P[((k >> 2) * HID + o) * 4 + (k & 3)] = W1[tid];
    }
    if (tid < LAT * HID) {              // W2: o in [0,128), k in [0,256)
        int o = tid / HID, k = tid % HID;
        W2P[((k >> 2) * LAT + o) * 4 + (k & 3)] = W2[tid];
    }
    if (tid < G3 * LAT) {               // Whh: o in [0,384), k in [0,128)
        int o = tid / LAT, k = tid % LAT;
        WhhP[((k >> 2) * G3 + o) * 4 + (k & 3)] = Whh[tid];
    }
}

#define GS_STRIDE 385   // g_s row stride (+1 pad)

__global__ __launch_bounds__(NTHR)
void odernn_kernel(const float* __restrict__ times,
                   const float* __restrict__ vals,
                   const float* __restrict__ mask,
                   const float* __restrict__ W1P, const float* __restrict__ b1,
                   const float* __restrict__ W2P, const float* __restrict__ b2,
                   const float* __restrict__ W_ih, const float* __restrict__ b_ih,
                   const float* __restrict__ WhhP, const float* __restrict__ b_hh,
                   float* __restrict__ out)
{
    __shared__ float h_s[MB][LAT];            // 4 KB
    __shared__ float u_s[MB][HID];            // 8 KB
    __shared__ float g_s[MB * GS_STRIDE];     // ~12 KB
    __shared__ float ps[MB * 8 * 128];        // 32 KB, reused by all 3 phases
    // total ~56 KB < 64 KB

    const int tid   = threadIdx.x;
    const int fbase = blockIdx.x * MB;

    const float4* W1v = (const float4*)W1P;
    const float4* W2v = (const float4*)W2P;
    const float4* Whv = (const float4*)WhhP;

    // phase-4 per-thread constants (loop-invariant): this thread owns (m4, k4)
    const int m4 = tid >> 7;
    const int k4 = tid & 127;
    const float wih_r = W_ih[k4],           bih_r = b_ih[k4];
    const float wih_z = W_ih[LAT + k4],     bih_z = b_ih[LAT + k4];
    const float wih_n = W_ih[2 * LAT + k4], bih_n = b_ih[2 * LAT + k4];

    h_s[m4][k4] = 0.0f;   // exactly MB*LAT = 1024 elements
    __syncthreads();

    for (int t = 0; t < T_STEPS; ++t) {
        const float dt = (t == 0) ? 0.0f
                         : (times[T_STEPS - t] - times[T_STEPS - 1 - t]);

        if (dt > 0.0f) {
            // ---- phase 1: u = tanh(h @ W1^T + b1). 256 outputs x 4-way K-split
            {
                const int j  = tid & 255;
                const int kq = tid >> 8;          // 0..3, 32 k's each
                float acc[MB];
                #pragma unroll
                for (int m = 0; m < MB; ++m) acc[m] = 0.0f;
                #pragma unroll
                for (int i4 = 0; i4 < 8; ++i4) {
                    const float4 w = W1v[(kq * 8 + i4) * HID + j];
                    const int k = kq * 32 + i4 * 4;
                    #pragma unroll
                    for (int m = 0; m < MB; ++m) {
                        const float4 h4 = *(const float4*)(&h_s[m][k]);
                        acc[m] = fmaf(w.x, h4.x, acc[m]);
                        acc[m] = fmaf(w.y, h4.y, acc[m]);
                        acc[m] = fmaf(w.z, h4.z, acc[m]);
                        acc[m] = fmaf(w.w, h4.w, acc[m]);
                    }
                }
                #pragma unroll
                for (int m = 0; m < MB; ++m) ps[(m * 4 + kq) * 256 + j] = acc[m];
            }
            __syncthreads();
            {   // reduce: 2048 (j,m) pairs over 1024 threads, 2 m's each
                const int j  = tid & 255;
                const int mg = tid >> 8;
                const float bj = b1[j];
                #pragma unroll
                for (int mi = 0; mi < 2; ++mi) {
                    const int m = mg * 2 + mi;
                    float v = bj;
                    #pragma unroll
                    for (int q = 0; q < 4; ++q) v += ps[(m * 4 + q) * 256 + j];
                    u_s[m][j] = tanhf_(v);
                }
            }
            __syncthreads();

            // ---- phase 2: ode = u @ W2^T + b2. 128 outputs x 8-way K-split
            {
                const int p  = tid & 127;
                const int kq = tid >> 7;          // 0..7, 32 k's each
                float acc[MB];
                #pragma unroll
                for (int m = 0; m < MB; ++m) acc[m] = 0.0f;
                #pragma unroll
                for (int i4 = 0; i4 < 8; ++i4) {
                    const float4 w = W2v[(kq * 8 + i4) * LAT + p];
                    const int k = kq * 32 + i4 * 4;
                    #pragma unroll
                    for (int m = 0; m < MB; ++m) {
                        const float4 u4 = *(const float4*)(&u_s[m][k]);
                        acc[m] = fmaf(w.x, u4.x, acc[m]);
                        acc[m] = fmaf(w.y, u4.y, acc[m]);
                        acc[m] = fmaf(w.z, u4.z, acc[m]);
                        acc[m] = fmaf(w.w, u4.w, acc[m]);
                    }
                }
                #pragma unroll
                for (int m = 0; m < MB; ++m) ps[(m * 8 + kq) * 128 + p] = acc[m];
            }
            __syncthreads();
            {   // reduce + h += dt*ode : exactly 1024 (p,m) pairs
                const int p = tid & 127;
                const int m = tid >> 7;
                float v = b2[p];
                #pragma unroll
                for (int q = 0; q < 8; ++q) v += ps[(m * 8 + q) * 128 + p];
                h_s[m][p] = fmaf(dt, v, h_s[m][p]);
            }
            __syncthreads();
        }

        // ---- phase 3: gh = h @ Whh^T + b_hh. one pass:
        // threads 0..767 active: output o = tid - kq*384, 2-way K-split (64 k's)
        if (tid < 768) {
            const int kq = (tid >= 384) ? 1 : 0;
            const int o  = tid - kq * 384;
            float acc[MB];
            #pragma unroll
            for (int m = 0; m < MB; ++m) acc[m] = 0.0f;
            #pragma unroll
            for (int i4 = 0; i4 < 16; ++i4) {
                const float4 w = Whv[(kq * 16 + i4) * G3 + o];
                const int k = kq * 64 + i4 * 4;
                #pragma unroll
                for (int m = 0; m < MB; ++m) {
                    const float4 h4 = *(const float4*)(&h_s[m][k]);
                    acc[m] = fmaf(w.x, h4.x, acc[m]);
                    acc[m] = fmaf(w.y, h4.y, acc[m]);
                    acc[m] = fmaf(w.z, h4.z, acc[m]);
                    acc[m] = fmaf(w.w, h4.w, acc[m]);
                }
            }
            #pragma unroll
            for (int m = 0; m < MB; ++m) ps[(kq * 8 + m) * 384 + o] = acc[m];
        }
        __syncthreads();
        {   // reduce into g_s: 3072 (o,m) pairs, 3 per thread (coalesced in o)
            const int p = tid & 127;
            const int m = tid >> 7;
            #pragma unroll
            for (int pass = 0; pass < 3; ++pass) {
                const int o = pass * 128 + p;
                const float v = b_hh[o] + ps[m * 384 + o] + ps[(8 + m) * 384 + o];
                g_s[m * GS_STRIDE + o] = v;
            }
        }
        __syncthreads();

        // ---- phase 4: elementwise GRU update with mask. 1 element/thread
        {
            const size_t rowoff = (size_t)(T_STEPS - 1 - t) * FDIM + fbase;
            const float x   = vals[rowoff + m4];
            const float mk  = mask[rowoff + m4];
            const float hv  = h_s[m4][k4];
            const float gir = fmaf(x, wih_r, bih_r);
            const float giz = fmaf(x, wih_z, bih_z);
            const float gin = fmaf(x, wih_n, bih_n);
            const float r   = sigmoidf_(gir + g_s[m4 * GS_STRIDE + k4]);
            const float z   = sigmoidf_(giz + g_s[m4 * GS_STRIDE + LAT + k4]);
            const float n   = tanhf_(fmaf(r, g_s[m4 * GS_STRIDE + 2 * LAT + k4], gin));
            const float hc  = (1.0f - z) * n + z * hv;
            h_s[m4][k4] = mk * hc + (1.0f - mk) * hv;
        }
        __syncthreads();
    }

    out[(size_t)(fbase + m4) * LAT + k4] = h_s[m4][k4];
}

extern "C" void kernel_launch(void* const* d_in, const int* in_sizes, int n_in,
                              void* d_out, int out_size, void* d_ws, size_t ws_size,
                              hipStream_t stream) {
    const float* times = (const float*)d_in[0];
    const float* vals  = (const float*)d_in[1];
    const float* mask  = (const float*)d_in[2];
    const float* W1    = (const float*)d_in[3];
    const float* b1    = (const float*)d_in[4];
    const float* W2    = (const float*)d_in[5];
    const float* b2    = (const float*)d_in[6];
    const float* W_ih  = (const float*)d_in[7];
    const float* b_ih  = (const float*)d_in[8];
    const float* Whh   = (const float*)d_in[9];
    const float* b_hh  = (const float*)d_in[10];
    float* out = (float*)d_out;

    float* W1P  = (float*)d_ws;            // 32768 floats
    float* W2P  = W1P + HID * LAT;         // 32768 floats
    float* WhhP = W2P + LAT * HID;         // 49152 floats  (total 448 KiB)

    prep_weights<<<(G3 * LAT + 255) / 256, 256, 0, stream>>>(W1, W2, Whh, W1P, W2P, WhhP);
    odernn_kernel<<<FDIM / MB, NTHR, 0, stream>>>(times, vals, mask,
                                                  W1P, b1, W2P, b2,
                                                  W_ih, b_ih, WhhP, b_hh, out);
}

// Round 4
// 2879.057 us; speedup vs baseline: 10.7249x; 4.8345x over previous
//
#include <hip/hip_runtime.h>

#define T_STEPS 1024
#define FDIM    2048
#define LAT     128
#define HID     256
#define G3      384
#define MB      16        // features per block -> M=16 matches MFMA tile
#define NTHR    1024      // 16 waves
#define NBLK    (FDIM / MB)   // 128 blocks

// LDS row strides (elements), padded so 16-lane access groups are <=2-way
#define HB_STR  136   // h bf16 shadow (stride*2B = 272B, 16B-aligned)
#define HF_STR  132   // h fp32 master
#define U_STR   264   // u bf16 (stride*2B = 528B)
#define G_STR   388   // gh fp32
#define SCR_TW  272   // scr tile stride words (16 rows * 17)

typedef __attribute__((ext_vector_type(8))) short bf16x8;
typedef __attribute__((ext_vector_type(4))) float f32x4;

__device__ __forceinline__ float sigmoidf_(float x) {
    return 1.0f / (1.0f + __expf(-x));
}
__device__ __forceinline__ float tanhf_(float x) {
    float ax = fabsf(x);
    float e  = __expf(-2.0f * ax);
    float t  = (1.0f - e) / (1.0f + e);
    return copysignf(t, x);
}
// fp32 -> bf16 bits, round-to-nearest-even
__device__ __forceinline__ short f2b(float x) {
    unsigned u = __float_as_uint(x);
    u += 0x7fffu + ((u >> 16) & 1u);
    return (short)(u >> 16);
}

__global__ __launch_bounds__(NTHR)
void odernn_kernel(const float* __restrict__ times,
                   const float* __restrict__ vals,
                   const float* __restrict__ mask,
                   const float* __restrict__ W1,  const float* __restrict__ b1,
                   const float* __restrict__ W2,  const float* __restrict__ b2,
                   const float* __restrict__ W_ih, const float* __restrict__ b_ih,
                   const float* __restrict__ Whh, const float* __restrict__ b_hh,
                   float* __restrict__ out)
{
    __shared__ float dts_s[T_STEPS];            // 4096 B
    __shared__ short h_b[MB * HB_STR];          // 4352 B  bf16 shadow of h
    __shared__ float h_f[MB * HF_STR];          // 8448 B  fp32 master h
    __shared__ short u_b[MB * U_STR];           // 8448 B  u = tanh(W1 h + b1), bf16
    __shared__ float g_s[MB * G_STR];           // 24832 B gh preacts fp32
    __shared__ float scr[8 * SCR_TW];           // 8704 B  phase-2 split-K partials
    // total ~58.9 KB

    const int tid  = threadIdx.x;
    const int w    = tid >> 6;        // wave 0..15
    const int ln   = tid & 63;
    const int col  = ln & 15;         // MFMA N (or M for A) lane index
    const int qd   = ln >> 4;         // quad 0..3
    const int rowb = qd * 4;          // C/D row base: row = rowb + reg
    const int fbase = blockIdx.x * MB;

    // ---------- prologue ----------
    for (int e = tid; e < T_STEPS; e += NTHR)
        dts_s[e] = (e == 0) ? 0.0f : (times[T_STEPS - e] - times[T_STEPS - 1 - e]);
    for (int e = tid; e < MB * LAT; e += NTHR) {   // 2 iters
        const int m = e >> 7, k = e & 127;
        h_f[m * HF_STR + k] = 0.0f;
        h_b[m * HB_STR + k] = 0;
    }

    // B-fragment loader: W is [NOUT][K] row-major (== B^T form).
    // Frag for tile base tb, k-block kb: lane holds W[tb+col][kb*32 + qd*8 + j]
    auto loadBfrag = [&](const float* __restrict__ W, int K, int tb, int kb) -> bf16x8 {
        const float* p = W + (size_t)(tb + col) * K + kb * 32 + qd * 8;
        const float4 a = *(const float4*)p;
        const float4 b = *(const float4*)(p + 4);
        bf16x8 r;
        r[0] = f2b(a.x); r[1] = f2b(a.y); r[2] = f2b(a.z); r[3] = f2b(a.w);
        r[4] = f2b(b.x); r[5] = f2b(b.y); r[6] = f2b(b.z); r[7] = f2b(b.w);
        return r;
    };

    // phase-1 weights: wave w owns u-cols [16w,16w+16), K=128 -> 4 frags
    bf16x8 w1f[4];
    #pragma unroll
    for (int kb = 0; kb < 4; ++kb) w1f[kb] = loadBfrag(W1, LAT, w * 16, kb);
    const float b1v = b1[w * 16 + col];

    // phase-2 weights: tile n=(w&7), k-half kh=(w>>3): 4 frags of K=128 half
    const int p2t  = w & 7;
    const int p2kh = w >> 3;
    bf16x8 w2f[4];
    #pragma unroll
    for (int kb = 0; kb < 4; ++kb)
        w2f[kb] = loadBfrag(W2, HID, p2t * 16, p2kh * 4 + kb);
    const float b2v = (p2kh == 0) ? b2[p2t * 16 + col] : 0.0f;

    // phase-3 weights: wave w -> tile w; waves 8..15 also tile w+8
    bf16x8 whf0[4], whf1[4];
    #pragma unroll
    for (int kb = 0; kb < 4; ++kb) whf0[kb] = loadBfrag(Whh, LAT, w * 16, kb);
    const float bh0 = b_hh[w * 16 + col];
    float bh1 = 0.0f;
    if (w >= 8) {
        #pragma unroll
        for (int kb = 0; kb < 4; ++kb) whf1[kb] = loadBfrag(Whh, LAT, (w + 8) * 16, kb);
        bh1 = b_hh[(w + 8) * 16 + col];
    }

    // phase-4 constants: thread owns (m4, k4) and (m4+8, k4) -> same k
    const int m4 = tid >> 7;          // 0..7
    const int k4 = tid & 127;
    const float wr = W_ih[k4],       br = b_ih[k4];
    const float wz = W_ih[128 + k4], bz = b_ih[128 + k4];
    const float wn = W_ih[256 + k4], bn = b_ih[256 + k4];

    // A-fragment loader from bf16 LDS [M][K] with row stride str
    auto loadAfrag = [&](const short* base, int str, int kboff) -> bf16x8 {
        return *(const bf16x8*)(base + col * str + kboff * 32 + qd * 8);
    };

    __syncthreads();

    for (int t = 0; t < T_STEPS; ++t) {
        const float dt = dts_s[t];

        // prefetch phase-4 observations early (hide global latency)
        const size_t rowoff = (size_t)(T_STEPS - 1 - t) * FDIM + fbase;
        const float x0  = vals[rowoff + m4];
        const float mk0 = mask[rowoff + m4];
        const float x1  = vals[rowoff + m4 + 8];
        const float mk1 = mask[rowoff + m4 + 8];

        if (dt > 0.0f) {
            // ---- phase 1: u = tanh(h @ W1^T + b1) ----
            f32x4 acc = {0.f, 0.f, 0.f, 0.f};
            #pragma unroll
            for (int kb = 0; kb < 4; ++kb)
                acc = __builtin_amdgcn_mfma_f32_16x16x32_bf16(
                          loadAfrag(h_b, HB_STR, kb), w1f[kb], acc, 0, 0, 0);
            #pragma unroll
            for (int r = 0; r < 4; ++r)
                u_b[(rowb + r) * U_STR + w * 16 + col] = f2b(tanhf_(acc[r] + b1v));
            __syncthreads();

            // ---- phase 2: ode = u @ W2^T + b2, 2-way split-K ----
            f32x4 a2 = {0.f, 0.f, 0.f, 0.f};
            #pragma unroll
            for (int kb = 0; kb < 4; ++kb)
                a2 = __builtin_amdgcn_mfma_f32_16x16x32_bf16(
                         loadAfrag(u_b, U_STR, p2kh * 4 + kb), w2f[kb], a2, 0, 0, 0);
            if (p2kh == 1) {
                #pragma unroll
                for (int r = 0; r < 4; ++r)
                    scr[p2t * SCR_TW + (rowb + r) * 17 + col] = a2[r];
            }
            __syncthreads();
            if (p2kh == 0) {
                #pragma unroll
                for (int r = 0; r < 4; ++r) {
                    const int mrow = rowb + r, cc = p2t * 16 + col;
                    const float ode = a2[r] + scr[p2t * SCR_TW + mrow * 17 + col] + b2v;
                    float hv = h_f[mrow * HF_STR + cc];
                    hv = fmaf(dt, ode, hv);
                    h_f[mrow * HF_STR + cc] = hv;
                    h_b[mrow * HB_STR + cc] = f2b(hv);
                }
            }
            __syncthreads();
        }

        // ---- phase 3: gh = h @ Whh^T + b_hh (384 outputs, 24 tiles) ----
        {
            f32x4 a3 = {0.f, 0.f, 0.f, 0.f};
            #pragma unroll
            for (int kb = 0; kb < 4; ++kb)
                a3 = __builtin_amdgcn_mfma_f32_16x16x32_bf16(
                         loadAfrag(h_b, HB_STR, kb), whf0[kb], a3, 0, 0, 0);
            #pragma unroll
            for (int r = 0; r < 4; ++r)
                g_s[(rowb + r) * G_STR + w * 16 + col] = a3[r] + bh0;
            if (w >= 8) {
                f32x4 a4 = {0.f, 0.f, 0.f, 0.f};
                #pragma unroll
                for (int kb = 0; kb < 4; ++kb)
                    a4 = __builtin_amdgcn_mfma_f32_16x16x32_bf16(
                             loadAfrag(h_b, HB_STR, kb), whf1[kb], a4, 0, 0, 0);
                #pragma unroll
                for (int r = 0; r < 4; ++r)
                    g_s[(rowb + r) * G_STR + (w + 8) * 16 + col] = a4[r] + bh1;
            }
        }
        __syncthreads();

        // ---- phase 4: elementwise GRU, 2 elements/thread ----
        {
            #pragma unroll
            for (int h2 = 0; h2 < 2; ++h2) {
                const int m = m4 + h2 * 8;
                const float x  = h2 ? x1 : x0;
                const float mk = h2 ? mk1 : mk0;
                float hv = h_f[m * HF_STR + k4];
                const float rr = sigmoidf_(fmaf(x, wr, br) + g_s[m * G_STR + k4]);
                const float zz = sigmoidf_(fmaf(x, wz, bz) + g_s[m * G_STR + 128 + k4]);
                const float nn = tanhf_(fmaf(rr, g_s[m * G_STR + 256 + k4],
                                             fmaf(x, wn, bn)));
                const float hc = (1.0f - zz) * nn + zz * hv;
                hv = mk * hc + (1.0f - mk) * hv;
                h_f[m * HF_STR + k4] = hv;
                h_b[m * HB_STR + k4] = f2b(hv);
            }
        }
        __syncthreads();
    }

    #pragma unroll
    for (int h2 = 0; h2 < 2; ++h2) {
        const int m = m4 + h2 * 8;
        out[(size_t)(fbase + m) * LAT + k4] = h_f[m * HF_STR + k4];
    }
}

extern "C" void kernel_launch(void* const* d_in, const int* in_sizes, int n_in,
                              void* d_out, int out_size, void* d_ws, size_t ws_size,
                              hipStream_t stream) {
    const float* times = (const float*)d_in[0];
    const float* vals  = (const float*)d_in[1];
    const float* mask  = (const float*)d_in[2];
    const float* W1    = (const float*)d_in[3];
    const float* b1    = (const float*)d_in[4];
    const float* W2    = (const float*)d_in[5];
    const float* b2    = (const float*)d_in[6];
    const float* W_ih  = (const float*)d_in[7];
    const float* b_ih  = (const float*)d_in[8];
    const float* Whh   = (const float*)d_in[9];
    const float* b_hh  = (const float*)d_in[10];
    float* out = (float*)d_out;

    odernn_kernel<<<NBLK, NTHR, 0, stream>>>(times, vals, mask,
                                             W1, b1, W2, b2,
                                             W_ih, b_ih, Whh, b_hh, out);
}

// Round 5
// 2140.126 us; speedup vs baseline: 14.4280x; 1.3453x over previous
//
#include <hip/hip_runtime.h>

#define T_STEPS 1024
#define FDIM    2048
#define LAT     128
#define HID     256
#define G3      384
#define MB      8             // features per block (rows 0..7 of the M=16 tile)
#define NTHR    512           // 8 waves
#define NBLK    (FDIM / MB)   // 256 blocks -> 1 per CU

#define HF_STR  132           // h fp32 master row stride (bank step 4 -> <=2-way)
#define G_STR   388           // gh fp32 row stride (bank step 4 -> <=2-way)

typedef __attribute__((ext_vector_type(8))) short bf16x8;
typedef __attribute__((ext_vector_type(4))) float f32x4;

__device__ __forceinline__ float sigmoidf_(float x) {
    return 1.0f / (1.0f + __expf(-x));
}
__device__ __forceinline__ float tanhf_(float x) {
    float ax = fabsf(x);
    float e  = __expf(-2.0f * ax);
    float t  = (1.0f - e) / (1.0f + e);
    return copysignf(t, x);
}
// fp32 -> bf16 bits, round-to-nearest-even
__device__ __forceinline__ short f2b(float x) {
    unsigned u = __float_as_uint(x);
    u += 0x7fffu + ((u >> 16) & 1u);
    return (short)(u >> 16);
}
// fragment-linear LDS offset for element (m, k): A-frag reads become contiguous
__device__ __forceinline__ int fragIdx(int m, int k) {
    return ((k >> 3) << 7) + (m << 3) + (k & 7);
}

__global__ __launch_bounds__(NTHR)
void odernn_kernel(const float* __restrict__ times,
                   const float* __restrict__ vals,
                   const float* __restrict__ mask,
                   const float* __restrict__ W1,  const float* __restrict__ b1,
                   const float* __restrict__ W2,  const float* __restrict__ b2,
                   const float* __restrict__ W_ih, const float* __restrict__ b_ih,
                   const float* __restrict__ Whh, const float* __restrict__ b_hh,
                   float* __restrict__ out)
{
    __shared__ float dts_s[T_STEPS];        // 4 KB
    __shared__ short h_b[16 * LAT];         // 4 KB  bf16 h, fragment-linear (16 rows alloc)
    __shared__ short u_b[32 * LAT];         // 8 KB  bf16 u, fragment-linear (K=256 -> 32 groups)
    __shared__ float h_f[MB * HF_STR];      // 4.1 KB fp32 master h
    __shared__ float g_s[MB * G_STR];       // 12.1 KB gh preacts
    // total ~33 KB

    const int tid  = threadIdx.x;
    const int w    = tid >> 6;      // wave 0..7
    const int ln   = tid & 63;
    const int col  = ln & 15;       // MFMA lane col (N for B/C, M for A)
    const int qd   = ln >> 4;       // quad 0..3
    const int fbase = blockIdx.x * MB;

    // ---------- prologue ----------
    for (int e = tid; e < T_STEPS; e += NTHR)
        dts_s[e] = (e == 0) ? 0.0f : (times[T_STEPS - e] - times[T_STEPS - 1 - e]);
    for (int e = tid; e < 16 * LAT; e += NTHR) h_b[e] = 0;
    for (int e = tid; e < 32 * LAT; e += NTHR) u_b[e] = 0;
    for (int e = tid; e < MB * HF_STR; e += NTHR) h_f[e] = 0.0f;

    // B-fragment loader: W is [NOUT][K] row-major (== B^T). Lane holds
    // W[tb+col][kb*32 + qd*8 + j], j=0..7
    auto loadBfrag = [&](const float* __restrict__ W, int K, int tb, int kb) -> bf16x8 {
        const float* p = W + (size_t)(tb + col) * K + kb * 32 + qd * 8;
        const float4 a = *(const float4*)p;
        const float4 b = *(const float4*)(p + 4);
        bf16x8 r;
        r[0] = f2b(a.x); r[1] = f2b(a.y); r[2] = f2b(a.z); r[3] = f2b(a.w);
        r[4] = f2b(b.x); r[5] = f2b(b.y); r[6] = f2b(b.z); r[7] = f2b(b.w);
        return r;
    };

    // phase-1 weights: wave w -> u-col tiles {2w, 2w+1}, K=128 (4 frags each)
    bf16x8 w1f[2][4]; float b1v[2];
    #pragma unroll
    for (int i = 0; i < 2; ++i) {
        #pragma unroll
        for (int kb = 0; kb < 4; ++kb) w1f[i][kb] = loadBfrag(W1, LAT, (2 * w + i) * 16, kb);
        b1v[i] = b1[(2 * w + i) * 16 + col];
    }
    // phase-2 weights: wave w -> ode tile w, full K=256 (8 frags)
    bf16x8 w2f[8];
    #pragma unroll
    for (int kb = 0; kb < 8; ++kb) w2f[kb] = loadBfrag(W2, HID, w * 16, kb);
    const float b2v = b2[w * 16 + col];
    // phase-3 weights: wave w -> gh tiles {3w, 3w+1, 3w+2}, K=128
    bf16x8 whf[3][4]; float bhv[3];
    #pragma unroll
    for (int i = 0; i < 3; ++i) {
        #pragma unroll
        for (int kb = 0; kb < 4; ++kb) whf[i][kb] = loadBfrag(Whh, LAT, (3 * w + i) * 16, kb);
        bhv[i] = b_hh[(3 * w + i) * 16 + col];
    }

    // phase-4: thread owns (m4, kk) and (m4, kk+64); consecutive lanes vary m4
    const int m4 = tid & 7;
    const int kk = tid >> 3;      // 0..63
    float wih[2][3], bih[2][3];
    #pragma unroll
    for (int e = 0; e < 2; ++e) {
        const int k = kk + e * 64;
        wih[e][0] = W_ih[k];       bih[e][0] = b_ih[k];
        wih[e][1] = W_ih[128 + k]; bih[e][1] = b_ih[128 + k];
        wih[e][2] = W_ih[256 + k]; bih[e][2] = b_ih[256 + k];
    }

    __syncthreads();

    for (int t = 0; t < T_STEPS; ++t) {
        const float dt = dts_s[t];
        // prefetch observations (consumed ~1000 cyc later in phase 4)
        const size_t rowoff = (size_t)(T_STEPS - 1 - t) * FDIM + fbase;
        const float x  = vals[rowoff + m4];
        const float mk = mask[rowoff + m4];

        if (dt > 0.0f) {
            // ---- phase 1: u = tanh(h @ W1^T + b1) ----
            f32x4 a0 = {0.f,0.f,0.f,0.f}, a1 = {0.f,0.f,0.f,0.f};
            #pragma unroll
            for (int kb = 0; kb < 4; ++kb) {
                const bf16x8 af = *(const bf16x8*)(h_b + kb * 512 + ln * 8);
                a0 = __builtin_amdgcn_mfma_f32_16x16x32_bf16(af, w1f[0][kb], a0, 0, 0, 0);
                a1 = __builtin_amdgcn_mfma_f32_16x16x32_bf16(af, w1f[1][kb], a1, 0, 0, 0);
            }
            if (qd < 2) {
                #pragma unroll
                for (int r = 0; r < 4; ++r) {
                    const int m = qd * 4 + r;
                    { const int k = (2 * w) * 16 + col;
                      u_b[fragIdx(m, k)] = f2b(tanhf_(a0[r] + b1v[0])); }
                    { const int k = (2 * w + 1) * 16 + col;
                      u_b[fragIdx(m, k)] = f2b(tanhf_(a1[r] + b1v[1])); }
                }
            }
            __syncthreads();

            // ---- phase 2: ode = u @ W2^T + b2; h += dt*ode ----
            f32x4 a2 = {0.f,0.f,0.f,0.f};
            #pragma unroll
            for (int kb = 0; kb < 8; ++kb)
                a2 = __builtin_amdgcn_mfma_f32_16x16x32_bf16(
                         *(const bf16x8*)(u_b + kb * 512 + ln * 8), w2f[kb], a2, 0, 0, 0);
            if (qd < 2) {
                #pragma unroll
                for (int r = 0; r < 4; ++r) {
                    const int m = qd * 4 + r;
                    const int p = w * 16 + col;
                    float hv = fmaf(dt, a2[r] + b2v, h_f[m * HF_STR + p]);
                    h_f[m * HF_STR + p] = hv;
                    h_b[fragIdx(m, p)] = f2b(hv);
                }
            }
            __syncthreads();
        }

        // ---- phase 3: gh = h @ Whh^T + b_hh ----
        {
            f32x4 g0 = {0.f,0.f,0.f,0.f}, g1 = {0.f,0.f,0.f,0.f}, g2 = {0.f,0.f,0.f,0.f};
            #pragma unroll
            for (int kb = 0; kb < 4; ++kb) {
                const bf16x8 af = *(const bf16x8*)(h_b + kb * 512 + ln * 8);
                g0 = __builtin_amdgcn_mfma_f32_16x16x32_bf16(af, whf[0][kb], g0, 0, 0, 0);
                g1 = __builtin_amdgcn_mfma_f32_16x16x32_bf16(af, whf[1][kb], g1, 0, 0, 0);
                g2 = __builtin_amdgcn_mfma_f32_16x16x32_bf16(af, whf[2][kb], g2, 0, 0, 0);
            }
            if (qd < 2) {
                #pragma unroll
                for (int r = 0; r < 4; ++r) {
                    const int m = qd * 4 + r;
                    g_s[m * G_STR + (3 * w + 0) * 16 + col] = g0[r] + bhv[0];
                    g_s[m * G_STR + (3 * w + 1) * 16 + col] = g1[r] + bhv[1];
                    g_s[m * G_STR + (3 * w + 2) * 16 + col] = g2[r] + bhv[2];
                }
            }
        }
        __syncthreads();

        // ---- phase 4: elementwise GRU, 2 elements/thread (same m4) ----
        #pragma unroll
        for (int e = 0; e < 2; ++e) {
            const int k = kk + e * 64;
            float hv = h_f[m4 * HF_STR + k];
            const float rr = sigmoidf_(fmaf(x, wih[e][0], bih[e][0]) + g_s[m4 * G_STR + k]);
            const float zz = sigmoidf_(fmaf(x, wih[e][1], bih[e][1]) + g_s[m4 * G_STR + 128 + k]);
            const float nn = tanhf_(fmaf(rr, g_s[m4 * G_STR + 256 + k],
                                         fmaf(x, wih[e][2], bih[e][2])));
            const float hc = (1.0f - zz) * nn + zz * hv;
            hv = mk * hc + (1.0f - mk) * hv;
            h_f[m4 * HF_STR + k] = hv;
            h_b[fragIdx(m4, k)] = f2b(hv);
        }
        __syncthreads();
    }

    #pragma unroll
    for (int e = 0; e < 2; ++e) {
        const int k = kk + e * 64;
        out[(size_t)(fbase + m4) * LAT + k] = h_f[m4 * HF_STR + k];
    }
}

extern "C" void kernel_launch(void* const* d_in, const int* in_sizes, int n_in,
                              void* d_out, int out_size, void* d_ws, size_t ws_size,
                              hipStream_t stream) {
    const float* times = (const float*)d_in[0];
    const float* vals  = (const float*)d_in[1];
    const float* mask  = (const float*)d_in[2];
    const float* W1    = (const float*)d_in[3];
    const float* b1    = (const float*)d_in[4];
    const float* W2    = (const float*)d_in[5];
    const float* b2    = (const float*)d_in[6];
    const float* W_ih  = (const float*)d_in[7];
    const float* b_ih  = (const float*)d_in[8];
    const float* Whh   = (const float*)d_in[9];
    const float* b_hh  = (const float*)d_in[10];
    float* out = (float*)d_out;

    odernn_kernel<<<NBLK, NTHR, 0, stream>>>(times, vals, mask,
                                             W1, b1, W2, b2,
                                             W_ih, b_ih, Whh, b_hh, out);
}

// Round 6
// 2137.594 us; speedup vs baseline: 14.4451x; 1.0012x over previous
//
#include <hip/hip_runtime.h>

#define T_STEPS 1024
#define FDIM    2048
#define LAT     128
#define HID     256
#define G3      384
#define MB      8             // features per block (rows 0..7 of the M=16 tile)
#define NTHR    512           // 8 waves
#define NBLK    (FDIM / MB)   // 256 blocks -> 1 per CU

#define HF_STR  132           // h fp32 master row stride (bank step 4 -> <=2-way)
#define G_STR   388           // gh fp32 row stride (bank step 4 -> <=2-way)

typedef __attribute__((ext_vector_type(8))) short bf16x8;
typedef __attribute__((ext_vector_type(4))) float f32x4;

__device__ __forceinline__ float sigmoidf_(float x) {
    return 1.0f / (1.0f + __expf(-x));
}
__device__ __forceinline__ float tanhf_(float x) {
    float ax = fabsf(x);
    float e  = __expf(-2.0f * ax);
    float t  = (1.0f - e) / (1.0f + e);
    return copysignf(t, x);
}
// fp32 -> bf16 bits, round-to-nearest-even
__device__ __forceinline__ short f2b(float x) {
    unsigned u = __float_as_uint(x);
    u += 0x7fffu + ((u >> 16) & 1u);
    return (short)(u >> 16);
}
// fragment-linear LDS offset for element (m, k): A-frag reads become contiguous
__device__ __forceinline__ int fragIdx(int m, int k) {
    return ((k >> 3) << 7) + (m << 3) + (k & 7);
}

// launch_bounds(512, 2): 2 waves/EU min -> 256-VGPR cap. Weight fragments are
// 112 VGPRs/lane; the default 128-cap spilled them (R4: VALUBusy 59% of spill
// moves). Grid is 1 block/CU * 8 waves = 2 waves/EU, so 256 VGPRs costs nothing.
__global__ __launch_bounds__(NTHR, 2)
void odernn_kernel(const float* __restrict__ times,
                   const float* __restrict__ vals,
                   const float* __restrict__ mask,
                   const float* __restrict__ W1,  const float* __restrict__ b1,
                   const float* __restrict__ W2,  const float* __restrict__ b2,
                   const float* __restrict__ W_ih, const float* __restrict__ b_ih,
                   const float* __restrict__ Whh, const float* __restrict__ b_hh,
                   float* __restrict__ out)
{
    __shared__ float dts_s[T_STEPS];        // 4 KB
    __shared__ short h_b[16 * LAT];         // 4 KB  bf16 h, fragment-linear
    __shared__ short u_b[32 * LAT];         // 8 KB  bf16 u, fragment-linear
    __shared__ float h_f[MB * HF_STR];      // 4.1 KB fp32 master h
    __shared__ float g_s[MB * G_STR];       // 12.1 KB gh preacts
    // total ~33 KB

    const int tid  = threadIdx.x;
    const int w    = tid >> 6;      // wave 0..7
    const int ln   = tid & 63;
    const int col  = ln & 15;       // MFMA lane col (N for B/C, M for A)
    const int qd   = ln >> 4;       // quad 0..3
    const int fbase = blockIdx.x * MB;

    // ---------- prologue ----------
    for (int e = tid; e < T_STEPS; e += NTHR)
        dts_s[e] = (e == 0) ? 0.0f : (times[T_STEPS - e] - times[T_STEPS - 1 - e]);
    for (int e = tid; e < 16 * LAT; e += NTHR) h_b[e] = 0;
    for (int e = tid; e < 32 * LAT; e += NTHR) u_b[e] = 0;   // rows 8..15 stay 0
    for (int e = tid; e < MB * HF_STR; e += NTHR) h_f[e] = 0.0f;

    // B-fragment loader: W is [NOUT][K] row-major (== B^T). Lane holds
    // W[tb+col][kb*32 + qd*8 + j], j=0..7
    auto loadBfrag = [&](const float* __restrict__ W, int K, int tb, int kb) -> bf16x8 {
        const float* p = W + (size_t)(tb + col) * K + kb * 32 + qd * 8;
        const float4 a = *(const float4*)p;
        const float4 b = *(const float4*)(p + 4);
        bf16x8 r;
        r[0] = f2b(a.x); r[1] = f2b(a.y); r[2] = f2b(a.z); r[3] = f2b(a.w);
        r[4] = f2b(b.x); r[5] = f2b(b.y); r[6] = f2b(b.z); r[7] = f2b(b.w);
        return r;
    };

    // phase-1 weights: wave w -> u-col tiles {2w, 2w+1}, K=128 (4 frags each)
    bf16x8 w1f[2][4]; float b1v[2];
    #pragma unroll
    for (int i = 0; i < 2; ++i) {
        #pragma unroll
        for (int kb = 0; kb < 4; ++kb) w1f[i][kb] = loadBfrag(W1, LAT, (2 * w + i) * 16, kb);
        b1v[i] = b1[(2 * w + i) * 16 + col];
    }
    // phase-2 weights: wave w -> ode tile w, full K=256 (8 frags)
    bf16x8 w2f[8];
    #pragma unroll
    for (int kb = 0; kb < 8; ++kb) w2f[kb] = loadBfrag(W2, HID, w * 16, kb);
    const float b2v = b2[w * 16 + col];
    // phase-3 weights: wave w -> gh tiles {3w, 3w+1, 3w+2}, K=128
    bf16x8 whf[3][4]; float bhv[3];
    #pragma unroll
    for (int i = 0; i < 3; ++i) {
        #pragma unroll
        for (int kb = 0; kb < 4; ++kb) whf[i][kb] = loadBfrag(Whh, LAT, (3 * w + i) * 16, kb);
        bhv[i] = b_hh[(3 * w + i) * 16 + col];
    }

    // phase-4: thread owns (m4, kk) and (m4, kk+64); consecutive lanes vary m4
    const int m4 = tid & 7;
    const int kk = tid >> 3;      // 0..63
    float wih[2][3], bih[2][3];
    #pragma unroll
    for (int e = 0; e < 2; ++e) {
        const int k = kk + e * 64;
        wih[e][0] = W_ih[k];       bih[e][0] = b_ih[k];
        wih[e][1] = W_ih[128 + k]; bih[e][1] = b_ih[128 + k];
        wih[e][2] = W_ih[256 + k]; bih[e][2] = b_ih[256 + k];
    }

    __syncthreads();

    for (int t = 0; t < T_STEPS; ++t) {
        const float dt = dts_s[t];
        // prefetch observations (consumed ~1000 cyc later in phase 4)
        const size_t rowoff = (size_t)(T_STEPS - 1 - t) * FDIM + fbase;
        const float x  = vals[rowoff + m4];
        const float mk = mask[rowoff + m4];

        if (dt > 0.0f) {
            // ---- phase 1: u = tanh(h @ W1^T + b1) ----
            f32x4 a0 = {0.f,0.f,0.f,0.f}, a1 = {0.f,0.f,0.f,0.f};
            #pragma unroll
            for (int kb = 0; kb < 4; ++kb) {
                const bf16x8 af = *(const bf16x8*)(h_b + kb * 512 + ln * 8);
                a0 = __builtin_amdgcn_mfma_f32_16x16x32_bf16(af, w1f[0][kb], a0, 0, 0, 0);
                a1 = __builtin_amdgcn_mfma_f32_16x16x32_bf16(af, w1f[1][kb], a1, 0, 0, 0);
            }
            if (qd < 2) {
                #pragma unroll
                for (int r = 0; r < 4; ++r) {
                    const int m = qd * 4 + r;
                    { const int k = (2 * w) * 16 + col;
                      u_b[fragIdx(m, k)] = f2b(tanhf_(a0[r] + b1v[0])); }
                    { const int k = (2 * w + 1) * 16 + col;
                      u_b[fragIdx(m, k)] = f2b(tanhf_(a1[r] + b1v[1])); }
                }
            }
            __syncthreads();

            // ---- phase 2: ode = u @ W2^T + b2; h += dt*ode ----
            f32x4 a2 = {0.f,0.f,0.f,0.f};
            #pragma unroll
            for (int kb = 0; kb < 8; ++kb)
                a2 = __builtin_amdgcn_mfma_f32_16x16x32_bf16(
                         *(const bf16x8*)(u_b + kb * 512 + ln * 8), w2f[kb], a2, 0, 0, 0);
            if (qd < 2) {
                #pragma unroll
                for (int r = 0; r < 4; ++r) {
                    const int m = qd * 4 + r;
                    const int p = w * 16 + col;
                    float hv = fmaf(dt, a2[r] + b2v, h_f[m * HF_STR + p]);
                    h_f[m * HF_STR + p] = hv;
                    h_b[fragIdx(m, p)] = f2b(hv);
                }
            }
            __syncthreads();
        }

        // ---- phase 3: gh = h @ Whh^T + b_hh ----
        {
            f32x4 g0 = {0.f,0.f,0.f,0.f}, g1 = {0.f,0.f,0.f,0.f}, g2 = {0.f,0.f,0.f,0.f};
            #pragma unroll
            for (int kb = 0; kb < 4; ++kb) {
                const bf16x8 af = *(const bf16x8*)(h_b + kb * 512 + ln * 8);
                g0 = __builtin_amdgcn_mfma_f32_16x16x32_bf16(af, whf[0][kb], g0, 0, 0, 0);
                g1 = __builtin_amdgcn_mfma_f32_16x16x32_bf16(af, whf[1][kb], g1, 0, 0, 0);
                g2 = __builtin_amdgcn_mfma_f32_16x16x32_bf16(af, whf[2][kb], g2, 0, 0, 0);
            }
            if (qd < 2) {
                #pragma unroll
                for (int r = 0; r < 4; ++r) {
                    const int m = qd * 4 + r;
                    g_s[m * G_STR + (3 * w + 0) * 16 + col] = g0[r] + bhv[0];
                    g_s[m * G_STR + (3 * w + 1) * 16 + col] = g1[r] + bhv[1];
                    g_s[m * G_STR + (3 * w + 2) * 16 + col] = g2[r] + bhv[2];
                }
            }
        }
        __syncthreads();

        // ---- phase 4: elementwise GRU, 2 elements/thread (same m4) ----
        #pragma unroll
        for (int e = 0; e < 2; ++e) {
            const int k = kk + e * 64;
            float hv = h_f[m4 * HF_STR + k];
            const float rr = sigmoidf_(fmaf(x, wih[e][0], bih[e][0]) + g_s[m4 * G_STR + k]);
            const float zz = sigmoidf_(fmaf(x, wih[e][1], bih[e][1]) + g_s[m4 * G_STR + 128 + k]);
            const float nn = tanhf_(fmaf(rr, g_s[m4 * G_STR + 256 + k],
                                         fmaf(x, wih[e][2], bih[e][2])));
            const float hc = (1.0f - zz) * nn + zz * hv;
            hv = mk * hc + (1.0f - mk) * hv;
            h_f[m4 * HF_STR + k] = hv;
            h_b[fragIdx(m4, k)] = f2b(hv);
        }
        __syncthreads();
    }

    #pragma unroll
    for (int e = 0; e < 2; ++e) {
        const int k = kk + e * 64;
        out[(size_t)(fbase + m4) * LAT + k] = h_f[m4 * HF_STR + k];
    }
}

extern "C" void kernel_launch(void* const* d_in, const int* in_sizes, int n_in,
                              void* d_out, int out_size, void* d_ws, size_t ws_size,
                              hipStream_t stream) {
    const float* times = (const float*)d_in[0];
    const float* vals  = (const float*)d_in[1];
    const float* mask  = (const float*)d_in[2];
    const float* W1    = (const float*)d_in[3];
    const float* b1    = (const float*)d_in[4];
    const float* W2    = (const float*)d_in[5];
    const float* b2    = (const float*)d_in[6];
    const float* W_ih  = (const float*)d_in[7];
    const float* b_ih  = (const float*)d_in[8];
    const float* Whh   = (const float*)d_in[9];
    const float* b_hh  = (const float*)d_in[10];
    float* out = (float*)d_out;

    odernn_kernel<<<NBLK, NTHR, 0, stream>>>(times, vals, mask,
                                             W1, b1, W2, b2,
                                             W_ih, b_ih, Whh, b_hh, out);
}